// Round 1
// baseline (112.098 us; speedup 1.0000x reference)
//
#include <hip/hip_runtime.h>

// QPLayer: per-batch box-constrained dual QP solved by 400 fixed PGD iterations.
// Math: q = b (x cancels), M = 2*A*A^T (rank 4), L = 2*||A^T A||_F + 1e-6,
//       alpha = 1/L, lam <- relu(lam - alpha*(2*A*(A^T lam) + b)), out = -A^T lam.
// Decomposition: 4 lanes per problem; lane j owns rows 8j..8j+7 of A and the
// corresponding 8 lam entries. Cross-lane: quad-sum of the 4-vector u = A^T lam
// via DPP quad_perm (pure VALU, no LDS).

#define QP_ITERS 400

__device__ __forceinline__ float quad_sum(float v) {
    // butterfly within aligned 4-lane quads: after 2 stages all 4 lanes hold the sum
    int d = __builtin_amdgcn_update_dpp(0, __float_as_int(v), 0xB1, 0xF, 0xF, true); // quad_perm(1,0,3,2)
    v += __int_as_float(d);
    d = __builtin_amdgcn_update_dpp(0, __float_as_int(v), 0x4E, 0xF, 0xF, true);     // quad_perm(2,3,0,1)
    v += __int_as_float(d);
    return v;
}

__global__ __launch_bounds__(256) void qp_pgd_kernel(
        const float* __restrict__ A,   // [nprob, 32, 4]
        const float* __restrict__ b,   // [nprob, 32]
        float* __restrict__ out,       // [nprob, 4]
        int nprob) {
    int t = blockIdx.x * blockDim.x + threadIdx.x;
    int p = t >> 2;          // problem index
    int j = t & 3;           // lane within quad
    if (p >= nprob) return;

    // Lane j owns rows m = 8j .. 8j+7. A rows are 16B-aligned float4s.
    const float4* Ar = reinterpret_cast<const float4*>(A + (size_t)p * 128 + (size_t)j * 32);
    const float4* br = reinterpret_cast<const float4*>(b + (size_t)p * 32 + (size_t)j * 8);

    float ax[8], ay[8], az[8], aw[8];
#pragma unroll
    for (int k = 0; k < 8; ++k) {
        float4 r = Ar[k];
        ax[k] = r.x; ay[k] = r.y; az[k] = r.z; aw[k] = r.w;
    }
    float bb[8];
    {
        float4 b0 = br[0], b1 = br[1];
        bb[0] = b0.x; bb[1] = b0.y; bb[2] = b0.z; bb[3] = b0.w;
        bb[4] = b1.x; bb[5] = b1.y; bb[6] = b1.z; bb[7] = b1.w;
    }

    // ---- alpha = 1 / (2*||A^T A||_F + 1e-6) ----
    float s00 = 0.f, s01 = 0.f, s02 = 0.f, s03 = 0.f;
    float s11 = 0.f, s12 = 0.f, s13 = 0.f;
    float s22 = 0.f, s23 = 0.f, s33 = 0.f;
#pragma unroll
    for (int k = 0; k < 8; ++k) {
        s00 = fmaf(ax[k], ax[k], s00);
        s01 = fmaf(ax[k], ay[k], s01);
        s02 = fmaf(ax[k], az[k], s02);
        s03 = fmaf(ax[k], aw[k], s03);
        s11 = fmaf(ay[k], ay[k], s11);
        s12 = fmaf(ay[k], az[k], s12);
        s13 = fmaf(ay[k], aw[k], s13);
        s22 = fmaf(az[k], az[k], s22);
        s23 = fmaf(az[k], aw[k], s23);
        s33 = fmaf(aw[k], aw[k], s33);
    }
    s00 = quad_sum(s00); s01 = quad_sum(s01); s02 = quad_sum(s02); s03 = quad_sum(s03);
    s11 = quad_sum(s11); s12 = quad_sum(s12); s13 = quad_sum(s13);
    s22 = quad_sum(s22); s23 = quad_sum(s23); s33 = quad_sum(s33);
    float ssq = s00 * s00 + s11 * s11 + s22 * s22 + s33 * s33
              + 2.f * (s01 * s01 + s02 * s02 + s03 * s03
                     + s12 * s12 + s13 * s13 + s23 * s23);
    float L = 2.f * sqrtf(ssq) + 1e-6f;
    float alpha = 1.f / L;
    float ta = 2.f * alpha;

    float c[8];
#pragma unroll
    for (int k = 0; k < 8; ++k) c[k] = alpha * bb[k];

    // ---- 400 PGD iterations ----
    float lam[8];
#pragma unroll
    for (int k = 0; k < 8; ++k) lam[k] = 0.f;

    for (int it = 0; it < QP_ITERS; ++it) {
        // partial u = A^T lam over this lane's 8 rows (4 independent FMA chains)
        float u0 = 0.f, u1 = 0.f, u2 = 0.f, u3 = 0.f;
#pragma unroll
        for (int k = 0; k < 8; ++k) {
            u0 = fmaf(ax[k], lam[k], u0);
            u1 = fmaf(ay[k], lam[k], u1);
            u2 = fmaf(az[k], lam[k], u2);
            u3 = fmaf(aw[k], lam[k], u3);
        }
        u0 = quad_sum(u0); u1 = quad_sum(u1); u2 = quad_sum(u2); u3 = quad_sum(u3);
        float v0 = u0 * ta, v1 = u1 * ta, v2 = u2 * ta, v3 = u3 * ta;
        // lam[m] = relu(lam[m] - alpha*b[m] - 2*alpha*(A[m]·u))
#pragma unroll
        for (int k = 0; k < 8; ++k) {
            float tt = lam[k] - c[k];
            tt = fmaf(ax[k], -v0, tt);
            tt = fmaf(ay[k], -v1, tt);
            tt = fmaf(az[k], -v2, tt);
            tt = fmaf(aw[k], -v3, tt);
            lam[k] = fmaxf(tt, 0.f);
        }
    }

    // ---- output: out = -A^T lam ----
    float u0 = 0.f, u1 = 0.f, u2 = 0.f, u3 = 0.f;
#pragma unroll
    for (int k = 0; k < 8; ++k) {
        u0 = fmaf(ax[k], lam[k], u0);
        u1 = fmaf(ay[k], lam[k], u1);
        u2 = fmaf(az[k], lam[k], u2);
        u3 = fmaf(aw[k], lam[k], u3);
    }
    u0 = quad_sum(u0); u1 = quad_sum(u1); u2 = quad_sum(u2); u3 = quad_sum(u3);
    float r = (j & 1) ? ((j & 2) ? u3 : u1) : ((j & 2) ? u2 : u0);
    out[(size_t)p * 4 + j] = -r;
}

extern "C" void kernel_launch(void* const* d_in, const int* in_sizes, int n_in,
                              void* d_out, int out_size, void* d_ws, size_t ws_size,
                              hipStream_t stream) {
    const float* A = (const float*)d_in[0];
    // d_in[1] (x) cancels analytically and is unused.
    const float* b = (const float*)d_in[2];
    float* out = (float*)d_out;

    int nprob = in_sizes[2] / 32;          // B = 32768
    int threads = nprob * 4;               // 4 lanes per problem
    dim3 block(256);
    dim3 grid((threads + 255) / 256);
    hipLaunchKernelGGL(qp_pgd_kernel, grid, block, 0, stream, A, b, out, nprob);
}